// Round 3
// baseline (937.921 us; speedup 1.0000x reference)
//
#include <hip/hip_runtime.h>
#include <math.h>

#define N_NODES 100000
#define N_EDGES 1600000
#define D 128
#define NCLASS 10
#define NLAYERS 3
#define BN_EPS 1e-5f

#define LDA 136        // padded LDS row stride in bf16 elems
#define BUCKET_SH 7    // 128 nodes per bucket
#define NBUK 782       // ceil(100000/128)
#define BCAP 3072      // per-bucket edge capacity (mean 2046, +22 sigma)

typedef __attribute__((ext_vector_type(8))) short bf16x8;
typedef __attribute__((ext_vector_type(4))) float f32x4;

__device__ __forceinline__ ushort f2b(float x) {          // RNE fp32 -> bf16
    uint u = __float_as_uint(x);
    return (ushort)((u + 0x7fffu + ((u >> 16) & 1u)) >> 16);
}
__device__ __forceinline__ float b2f(uint u) {            // bf16 bits -> fp32 (exact)
    return __uint_as_float(u << 16);
}
__device__ __forceinline__ uint pack2(float a, float b) {
    return (uint)f2b(a) | ((uint)f2b(b) << 16);
}

// ---------------- CSR build: bucketed counting sort ----------------
// pass 1: scatter edges into per-bucket regions (packed src | d_local<<17)
__global__ void k_bucket_scatter(const int* __restrict__ src, const int* __restrict__ dst,
                                 int* __restrict__ bcur, uint* __restrict__ tmp) {
    int e = blockIdx.x * 256 + threadIdx.x;
    if (e < N_EDGES) {
        int d = dst[e];
        int b = d >> BUCKET_SH;
        int dl = d & ((1 << BUCKET_SH) - 1);
        int pos = atomicAdd(&bcur[b], 1);
        if (pos < BCAP)
            tmp[(size_t)b * BCAP + pos] = (uint)src[e] | ((uint)dl << 17);
    }
}

// pass 2: exclusive scan of bucket counts (782 values, one block)
__global__ void k_bscan(const int* __restrict__ bcur, int* __restrict__ bbase) {
    __shared__ int sh[1024];
    int t = threadIdx.x;
    int v = (t < NBUK) ? bcur[t] : 0;
    sh[t] = v; __syncthreads();
    for (int off = 1; off < 1024; off <<= 1) {
        int a = (t >= off) ? sh[t - off] : 0;
        __syncthreads();
        sh[t] += a;
        __syncthreads();
    }
    if (t < NBUK) bbase[t] = sh[t] - v;   // exclusive
}

// pass 3: per-bucket LDS histogram + scan -> row_ptr + csr fill (no global atomics)
__global__ __launch_bounds__(256) void k_bucket_fill(const uint* __restrict__ tmp,
                                                     const int* __restrict__ bcur,
                                                     const int* __restrict__ bbase,
                                                     int* __restrict__ row_ptr,
                                                     int* __restrict__ csr) {
    __shared__ int hist[128], inc[128], cur[128];
    int b = blockIdx.x, t = threadIdx.x;
    int nb = min(bcur[b], BCAP);
    int base = bbase[b];
    int lo = b << BUCKET_SH;
    const uint* bt = tmp + (size_t)b * BCAP;

    if (t < 128) hist[t] = 0;
    __syncthreads();
    for (int i = t; i < nb; i += 256)
        atomicAdd(&hist[bt[i] >> 17], 1);
    __syncthreads();
    if (t < 128) inc[t] = hist[t];
    __syncthreads();
    for (int off = 1; off < 128; off <<= 1) {
        int a = (t < 128 && t >= off) ? inc[t - off] : 0;
        __syncthreads();
        if (t < 128) inc[t] += a;
        __syncthreads();
    }
    if (t < 128) {
        int node = lo + t;
        if (node < N_NODES) row_ptr[node] = base + inc[t] - hist[t];
        cur[t] = 0;
    }
    if (b == NBUK - 1 && t == 0) row_ptr[N_NODES] = base + nb;
    __syncthreads();
    for (int i = t; i < nb; i += 256) {
        uint u = bt[i];
        int dl = u >> 17;
        int s = (int)(u & 0x1ffffu);
        int p = atomicAdd(&cur[dl], 1);
        csr[base + (inc[dl] - hist[dl]) + p] = s;
    }
}

// ---------------- fp32 -> bf16 bulk convert ----------------
__global__ void k_tobf16(const float* __restrict__ x, ushort* __restrict__ o) {
    int i = blockIdx.x * 256 + threadIdx.x;
    const int n4 = N_NODES * D / 4;
    if (i < n4) {
        float4 v = ((const float4*)x)[i];
        uint2 u;
        u.x = pack2(v.x, v.y);
        u.y = pack2(v.z, v.w);
        ((uint2*)o)[i] = u;
    }
}

// ---------------- aggregation (bf16 gather, fp32 accum, bf16 out) ----------------
__global__ __launch_bounds__(256) void k_aggregate(const ushort* __restrict__ hbf,
                                                   const int* __restrict__ row_ptr,
                                                   const int* __restrict__ csr,
                                                   ushort* __restrict__ outbf) {
    int node = blockIdx.x * 4 + (threadIdx.x >> 6);
    int lane = threadIdx.x & 63;
    const uint* hp = (const uint*)hbf;
    uint self = hp[(size_t)node * 64 + lane];
    float ax = b2f(self & 0xffffu), ay = b2f(self >> 16);
    int e0 = row_ptr[node], e1 = row_ptr[node + 1];
    int e = e0;
    for (; e + 7 < e1; e += 8) {
        uint v0 = hp[(size_t)csr[e]     * 64 + lane];
        uint v1 = hp[(size_t)csr[e + 1] * 64 + lane];
        uint v2 = hp[(size_t)csr[e + 2] * 64 + lane];
        uint v3 = hp[(size_t)csr[e + 3] * 64 + lane];
        uint v4 = hp[(size_t)csr[e + 4] * 64 + lane];
        uint v5 = hp[(size_t)csr[e + 5] * 64 + lane];
        uint v6 = hp[(size_t)csr[e + 6] * 64 + lane];
        uint v7 = hp[(size_t)csr[e + 7] * 64 + lane];
        ax += b2f(v0 & 0xffffu); ay += b2f(v0 >> 16);
        ax += b2f(v1 & 0xffffu); ay += b2f(v1 >> 16);
        ax += b2f(v2 & 0xffffu); ay += b2f(v2 >> 16);
        ax += b2f(v3 & 0xffffu); ay += b2f(v3 >> 16);
        ax += b2f(v4 & 0xffffu); ay += b2f(v4 >> 16);
        ax += b2f(v5 & 0xffffu); ay += b2f(v5 >> 16);
        ax += b2f(v6 & 0xffffu); ay += b2f(v6 >> 16);
        ax += b2f(v7 & 0xffffu); ay += b2f(v7 >> 16);
    }
    for (; e < e1; ++e) {
        uint v = hp[(size_t)csr[e] * 64 + lane];
        ax += b2f(v & 0xffffu); ay += b2f(v >> 16);
    }
    ((uint*)outbf)[(size_t)node * 64 + lane] = pack2(ax, ay);
}

// ---------------- MFMA GEMM ----------------
// A is bf16 [nrows][128]. PRE: 0 = copy; 2 = relu(a*scale[k]+shift[k]) on bf16 input.
// POST: 1 = relu. STATS: fused column sum/sumsq (on fp32 acc+bias, pre-rounding).
// Output bf16.
template <int PRE, int POST, int STATS>
__global__ __launch_bounds__(256, 2) void k_gemm(const ushort* __restrict__ inA,
                                                 const float* __restrict__ W,
                                                 const float* __restrict__ bias,
                                                 const float* __restrict__ scale,
                                                 const float* __restrict__ shift,
                                                 ushort* __restrict__ outp,
                                                 float* __restrict__ gsum,
                                                 float* __restrict__ gsq,
                                                 int nrows) {
    __shared__ ushort sA[128 * LDA];
    __shared__ ushort sB[128 * LDA];
    __shared__ float sbias[128];

    int t = threadIdx.x;
    int r0 = blockIdx.x * 128;

    // stage W [f][k] fp32 -> bf16 LDS
    for (int idx = t; idx < 128 * 32; idx += 256) {
        int f = idx >> 5, c4 = (idx & 31) << 2;
        float4 v = *(const float4*)(W + f * 128 + c4);
        ushort4 u;
        u.x = f2b(v.x); u.y = f2b(v.y); u.z = f2b(v.z); u.w = f2b(v.w);
        *(ushort4*)&sB[f * LDA + c4] = u;
    }
    if (t < 128) sbias[t] = bias[t];

    // stage A tile
    for (int idx = t; idx < 128 * 16; idx += 256) {
        int r = idx >> 4, c8 = (idx & 15) << 3;
        int rr = r0 + r;
        uint4 v = make_uint4(0u, 0u, 0u, 0u);
        if (rr < nrows) v = *(const uint4*)(inA + (size_t)rr * 128 + c8);
        if (PRE == 2) {
            float f0 = b2f(v.x & 0xffffu), f1 = b2f(v.x >> 16);
            float f2 = b2f(v.y & 0xffffu), f3 = b2f(v.y >> 16);
            float f4 = b2f(v.z & 0xffffu), f5 = b2f(v.z >> 16);
            float f6 = b2f(v.w & 0xffffu), f7 = b2f(v.w >> 16);
            float4 sc0 = *(const float4*)(scale + c8);
            float4 sc1 = *(const float4*)(scale + c8 + 4);
            float4 sf0 = *(const float4*)(shift + c8);
            float4 sf1 = *(const float4*)(shift + c8 + 4);
            f0 = fmaxf(fmaf(f0, sc0.x, sf0.x), 0.f);
            f1 = fmaxf(fmaf(f1, sc0.y, sf0.y), 0.f);
            f2 = fmaxf(fmaf(f2, sc0.z, sf0.z), 0.f);
            f3 = fmaxf(fmaf(f3, sc0.w, sf0.w), 0.f);
            f4 = fmaxf(fmaf(f4, sc1.x, sf1.x), 0.f);
            f5 = fmaxf(fmaf(f5, sc1.y, sf1.y), 0.f);
            f6 = fmaxf(fmaf(f6, sc1.z, sf1.z), 0.f);
            f7 = fmaxf(fmaf(f7, sc1.w, sf1.w), 0.f);
            v.x = pack2(f0, f1); v.y = pack2(f2, f3);
            v.z = pack2(f4, f5); v.w = pack2(f6, f7);
        }
        *(uint4*)&sA[r * LDA + c8] = v;
    }
    __syncthreads();

    int lane = t & 63, wid = t >> 6;
    int rl = lane & 15, g = lane >> 4;
    int wr = wid >> 1, wc = wid & 1;

    f32x4 acc[4][4];
#pragma unroll
    for (int i = 0; i < 4; ++i)
#pragma unroll
        for (int j = 0; j < 4; ++j) acc[i][j] = (f32x4){0.f, 0.f, 0.f, 0.f};

#pragma unroll
    for (int ks = 0; ks < 4; ++ks) {
        int koff = ks * 32 + g * 8;
        bf16x8 a[4], b[4];
#pragma unroll
        for (int mi = 0; mi < 4; ++mi)
            a[mi] = *(const bf16x8*)&sA[(wr * 64 + mi * 16 + rl) * LDA + koff];
#pragma unroll
        for (int ni = 0; ni < 4; ++ni)
            b[ni] = *(const bf16x8*)&sB[(wc * 64 + ni * 16 + rl) * LDA + koff];
#pragma unroll
        for (int mi = 0; mi < 4; ++mi)
#pragma unroll
            for (int ni = 0; ni < 4; ++ni)
                acc[mi][ni] = __builtin_amdgcn_mfma_f32_16x16x32_bf16(a[mi], b[ni], acc[mi][ni], 0, 0, 0);
    }

    float bn[4], ssum[4], ssq[4];
#pragma unroll
    for (int ni = 0; ni < 4; ++ni) {
        bn[ni] = sbias[wc * 64 + ni * 16 + rl];
        ssum[ni] = 0.f; ssq[ni] = 0.f;
    }

#pragma unroll
    for (int mi = 0; mi < 4; ++mi) {
        int orow = r0 + wr * 64 + mi * 16 + g * 4;
#pragma unroll
        for (int j = 0; j < 4; ++j) {
            int row = orow + j;
            if (row < nrows) {
#pragma unroll
                for (int ni = 0; ni < 4; ++ni) {
                    int ocol = wc * 64 + ni * 16 + rl;
                    float o = acc[mi][ni][j] + bn[ni];
                    if (STATS) { ssum[ni] += o; ssq[ni] += o * o; }
                    if (POST) o = fmaxf(o, 0.f);
                    outp[(size_t)row * 128 + ocol] = f2b(o);
                }
            }
        }
    }

    if (STATS) {
#pragma unroll
        for (int ni = 0; ni < 4; ++ni) {
            float s = ssum[ni], q = ssq[ni];
            s += __shfl_xor(s, 16, 64); q += __shfl_xor(q, 16, 64);
            s += __shfl_xor(s, 32, 64); q += __shfl_xor(q, 32, 64);
            if (g == 0) {
                int col = wc * 64 + ni * 16 + rl;
                atomicAdd(&gsum[col], s);
                atomicAdd(&gsq[col], q);
            }
        }
    }
}

// ---------------- BN finalize ----------------
__global__ void k_bnfin(const float* __restrict__ gsum, const float* __restrict__ gsq,
                        const float* __restrict__ gamma, const float* __restrict__ beta,
                        float* __restrict__ scale, float* __restrict__ shift) {
    int d = threadIdx.x;
    float mu = gsum[d] * (1.f / N_NODES);
    float var = gsq[d] * (1.f / N_NODES) - mu * mu;
    float rstd = rsqrtf(var + BN_EPS);
    float sc = rstd * gamma[d];
    scale[d] = sc;
    shift[d] = beta[d] - mu * sc;
}

// ---------------- head: out = sigmoid(tin @ lin2_W.T + lin2_b), tin bf16 ----------------
__global__ __launch_bounds__(128) void k_head2(const ushort* __restrict__ tin,
                                               const float* __restrict__ W2,
                                               const float* __restrict__ b2,
                                               float* __restrict__ out) {
    __shared__ float sh[128 * 130];
    __shared__ float w2s[NCLASS * 128];
    __shared__ float b2s[NCLASS];
    int t = threadIdx.x;
    int r0 = blockIdx.x * 128;

    for (int idx = t; idx < (NCLASS * 128) / 4; idx += 128) {
        float4 v = *(const float4*)(W2 + idx * 4);
        *(float4*)&w2s[idx * 4] = v;
    }
    if (t < NCLASS) b2s[t] = b2[t];

    const uint* tp = (const uint*)tin;
    for (int idx = t; idx < 128 * 64; idx += 128) {
        int r = idx >> 6, c2 = idx & 63;
        int rr = r0 + r;
        uint v = (rr < N_NODES) ? tp[(size_t)rr * 64 + c2] : 0u;
        sh[r * 130 + 2 * c2]     = b2f(v & 0xffffu);
        sh[r * 130 + 2 * c2 + 1] = b2f(v >> 16);
    }
    __syncthreads();

    float acc[NCLASS];
#pragma unroll
    for (int c = 0; c < NCLASS; ++c) acc[c] = 0.f;
    const float* myrow = &sh[t * 130];
#pragma unroll 4
    for (int k = 0; k < 128; ++k) {
        float v = myrow[k];
#pragma unroll
        for (int c = 0; c < NCLASS; ++c)
            acc[c] = fmaf(v, w2s[c * 128 + k], acc[c]);
    }
    int rr = r0 + t;
    if (rr < N_NODES) {
#pragma unroll
        for (int c = 0; c < NCLASS; ++c) {
            float z = acc[c] + b2s[c];
            out[(size_t)rr * NCLASS + c] = 1.f / (1.f + expf(-z));
        }
    }
}

// ---------------- launcher ----------------
extern "C" void kernel_launch(void* const* d_in, const int* in_sizes, int n_in,
                              void* d_out, int out_size, void* d_ws, size_t ws_size,
                              hipStream_t stream) {
    const float* x     = (const float*)d_in[0];
    const int*   ei    = (const int*)d_in[1];
    const float* W1    = (const float*)d_in[2];
    const float* b1    = (const float*)d_in[3];
    const float* gamma = (const float*)d_in[4];
    const float* beta  = (const float*)d_in[5];
    const float* W2    = (const float*)d_in[6];
    const float* b2    = (const float*)d_in[7];
    const float* l1W   = (const float*)d_in[8];
    const float* l1b   = (const float*)d_in[9];
    const float* l2W   = (const float*)d_in[10];
    const float* l2b   = (const float*)d_in[11];
    float* out = (float*)d_out;

    char* w = (char*)d_ws;
    ushort* hbf    = (ushort*)(w);                   // 25,600,000 B
    ushort* aggout = (ushort*)(w + 25600000);        // 25,600,000 B
    ushort* zbf    = (ushort*)(w + 51200000);        // 25,600,000 B
    int*   row_ptr = (int*)   (w + 76800000);        // 400,004 B (reserve 400,640)
    int*   csr     = (int*)   (w + 77200640);        // 6,400,000 B
    uint*  tmp     = (uint*)  (w + 83600640);        // 782*3072*4 = 9,609,216 B
    int*   bcur    = (int*)   (w + 93209856);        // reserve 4096
    int*   bbase   = (int*)   (w + 93213952);        // reserve 4096
    float* gsum    = (float*) (w + 93218048);        // 128 f
    float* gsq     = gsum + 128;
    float* scale   = gsum + 256;
    float* shift   = gsum + 384;

    const int* src = ei;
    const int* dst = ei + N_EDGES;

    const int GEMM_NB = (N_NODES + 127) / 128;       // 782

    // ---- CSR build (bucketed counting sort) ----
    hipMemsetAsync(bcur, 0, NBUK * sizeof(int), stream);
    k_bucket_scatter<<<(N_EDGES + 255) / 256, 256, 0, stream>>>(src, dst, bcur, tmp);
    k_bscan<<<1, 1024, 0, stream>>>(bcur, bbase);
    k_bucket_fill<<<NBUK, 256, 0, stream>>>(tmp, bcur, bbase, row_ptr, csr);

    // ---- x -> bf16 ----
    k_tobf16<<<(N_NODES * D / 4 + 255) / 256, 256, 0, stream>>>(x, hbf);

    // ---- 3 GIN layers ----
    for (int l = 0; l < NLAYERS; ++l) {
        k_aggregate<<<N_NODES / 4, 256, 0, stream>>>(hbf, row_ptr, csr, aggout);
        hipMemsetAsync(gsum, 0, 256 * sizeof(float), stream);
        // z = (h+agg) @ W1.T + b1  (bf16 out) + fused column stats (fp32)
        k_gemm<0, 0, 1><<<GEMM_NB, 256, 0, stream>>>(aggout, W1 + l * D * D, b1 + l * D,
                                                     nullptr, nullptr, zbf, gsum, gsq, N_NODES);
        k_bnfin<<<1, 128, 0, stream>>>(gsum, gsq, gamma + l * D, beta + l * D, scale, shift);
        // h' = relu( relu(BN(z)) @ W2.T + b2 )
        k_gemm<2, 1, 0><<<GEMM_NB, 256, 0, stream>>>(zbf, W2 + l * D * D, b2 + l * D,
                                                     scale, shift, hbf, nullptr, nullptr, N_NODES);
    }

    // ---- head ----
    k_gemm<0, 1, 0><<<GEMM_NB, 256, 0, stream>>>(hbf, l1W, l1b, nullptr, nullptr,
                                                 aggout, nullptr, nullptr, N_NODES);
    k_head2<<<GEMM_NB, 128, 0, stream>>>(aggout, l2W, l2b, out);
}